// Round 1
// baseline (3782.158 us; speedup 1.0000x reference)
//
#include <hip/hip_runtime.h>
#include <math.h>

#define B_ROWS 16384
#define D_IN   4096
#define HID    2048
#define NEXP   64

#define BM 128
#define BN 128
#define BK 16

// ---------------------------------------------------------------------------
// Kernel 1: h = silu(x @ W1 + b1)      [16384,4096] @ [4096,2048]
// 128x128 block tile, BK=16, 256 threads, 8x8 per-thread microtile.
// A staged transposed in LDS so the k-column read is contiguous.
// ---------------------------------------------------------------------------
__global__ __launch_bounds__(256) void gemm1_silu_kernel(
    const float* __restrict__ x, const float* __restrict__ W1,
    const float* __restrict__ b1, float* __restrict__ h)
{
    __shared__ float As[BK][BM + 4];   // [k][m], padded
    __shared__ float Bs[BK][BN];       // [k][n]

    const int tid = threadIdx.x;
    const int bx = blockIdx.x;         // HID tile 0..15
    const int by = blockIdx.y;         // row tile 0..127
    const int rowBase = by * BM;
    const int colBase = bx * BN;

    const int tx = tid & 15;
    const int ty = tid >> 4;

    float acc[8][8];
#pragma unroll
    for (int i = 0; i < 8; ++i)
#pragma unroll
        for (int j = 0; j < 8; ++j) acc[i][j] = 0.f;

    const int ar = tid >> 1;           // A row 0..127
    const int ak = (tid & 1) * 8;      // A k-offset 0 or 8
    const int bk = tid >> 4;           // B k-row 0..15
    const int bc = tid & 15;           // B float4 col

    for (int k0 = 0; k0 < D_IN; k0 += BK) {
        // A tile: x[rowBase+ar][k0+ak .. +8]  -> As[k][m] (transposed)
        {
            const float* src = &x[(size_t)(rowBase + ar) * D_IN + k0 + ak];
            float4 v0 = *reinterpret_cast<const float4*>(src);
            float4 v1 = *reinterpret_cast<const float4*>(src + 4);
            As[ak + 0][ar] = v0.x; As[ak + 1][ar] = v0.y;
            As[ak + 2][ar] = v0.z; As[ak + 3][ar] = v0.w;
            As[ak + 4][ar] = v1.x; As[ak + 5][ar] = v1.y;
            As[ak + 6][ar] = v1.z; As[ak + 7][ar] = v1.w;
        }
        // B tile: W1[k0+bk][colBase .. +128]
        {
            const float4* s4 = reinterpret_cast<const float4*>(
                &W1[(size_t)(k0 + bk) * HID + colBase]);
            float4* d4 = reinterpret_cast<float4*>(&Bs[bk][0]);
            d4[bc]      = s4[bc];
            d4[bc + 16] = s4[bc + 16];
        }
        __syncthreads();

#pragma unroll
        for (int kk = 0; kk < BK; ++kk) {
            float a[8], b[8];
            *reinterpret_cast<float4*>(&a[0]) =
                *reinterpret_cast<const float4*>(&As[kk][ty * 8]);
            *reinterpret_cast<float4*>(&a[4]) =
                *reinterpret_cast<const float4*>(&As[kk][ty * 8 + 4]);
            *reinterpret_cast<float4*>(&b[0]) =
                *reinterpret_cast<const float4*>(&Bs[kk][tx * 8]);
            *reinterpret_cast<float4*>(&b[4]) =
                *reinterpret_cast<const float4*>(&Bs[kk][tx * 8 + 4]);
#pragma unroll
            for (int i = 0; i < 8; ++i)
#pragma unroll
                for (int j = 0; j < 8; ++j)
                    acc[i][j] = fmaf(a[i], b[j], acc[i][j]);
        }
        __syncthreads();
    }

    // epilogue: bias + SiLU + store h
#pragma unroll
    for (int i = 0; i < 8; ++i) {
        const size_t row = (size_t)rowBase + ty * 8 + i;
        float o[8];
#pragma unroll
        for (int j = 0; j < 8; ++j) {
            float c = acc[i][j] + b1[colBase + tx * 8 + j];
            o[j] = c / (1.f + expf(-c));          // silu
        }
        float4* dst = reinterpret_cast<float4*>(&h[row * HID + colBase + tx * 8]);
        dst[0] = *reinterpret_cast<float4*>(&o[0]);
        dst[1] = *reinterpret_cast<float4*>(&o[4]);
    }
}

// ---------------------------------------------------------------------------
// Kernel 2: logits = h @ W2 + b2, then fused top-2 / softmax / routing stats.
// Block = 256 threads = 4 waves; each wave owns 8 rows, lane = expert.
// W2 staged in LDS in 64-k chunks, reused across the block's 32 rows.
// ---------------------------------------------------------------------------
__global__ __launch_bounds__(256) void router_kernel(
    const float* __restrict__ h, const float* __restrict__ W2,
    const float* __restrict__ b2, float* __restrict__ out,
    float* __restrict__ gFreq, float* __restrict__ gProb)
{
    __shared__ float W2s[64][NEXP];    // 16 KB chunk of W2
    __shared__ float sFreq[NEXP];
    __shared__ float sProb[NEXP];

    const int tid = threadIdx.x;
    const int lane = tid & 63;         // expert id
    const int wv = tid >> 6;           // wave id 0..3
    const int rowBase = blockIdx.x * 32;

    if (tid < NEXP) { sFreq[tid] = 0.f; sProb[tid] = 0.f; }

    float acc[8];
#pragma unroll
    for (int i = 0; i < 8; ++i) acc[i] = 0.f;

    const int wk = tid >> 2;           // W2 k-row 0..63
    const int wf = tid & 3;            // float4 group

    for (int k0 = 0; k0 < HID; k0 += 64) {
        __syncthreads();
        {
            const float4* src = reinterpret_cast<const float4*>(
                &W2[(size_t)(k0 + wk) * NEXP]);
            float4* dst = reinterpret_cast<float4*>(&W2s[wk][0]);
#pragma unroll
            for (int p = 0; p < 4; ++p) dst[wf + 4 * p] = src[wf + 4 * p];
        }
        __syncthreads();

#pragma unroll 2
        for (int kk4 = 0; kk4 < 16; ++kk4) {
            float4 hv[8];
#pragma unroll
            for (int i = 0; i < 8; ++i) {
                const size_t row = (size_t)rowBase + wv * 8 + i;
                hv[i] = *reinterpret_cast<const float4*>(
                    &h[row * HID + k0 + kk4 * 4]);
            }
            {
                const float w = W2s[kk4 * 4 + 0][lane];
#pragma unroll
                for (int i = 0; i < 8; ++i) acc[i] = fmaf(hv[i].x, w, acc[i]);
            }
            {
                const float w = W2s[kk4 * 4 + 1][lane];
#pragma unroll
                for (int i = 0; i < 8; ++i) acc[i] = fmaf(hv[i].y, w, acc[i]);
            }
            {
                const float w = W2s[kk4 * 4 + 2][lane];
#pragma unroll
                for (int i = 0; i < 8; ++i) acc[i] = fmaf(hv[i].z, w, acc[i]);
            }
            {
                const float w = W2s[kk4 * 4 + 3][lane];
#pragma unroll
                for (int i = 0; i < 8; ++i) acc[i] = fmaf(hv[i].w, w, acc[i]);
            }
        }
    }

    // ---- routing epilogue: per row, lanes hold logits[row][lane] ----
    float freqLocal = 0.f, probLocal = 0.f;
#pragma unroll
    for (int i = 0; i < 8; ++i) {
        const float v = acc[i] + b2[lane];

        // top-1: max with lowest-index tie-break (matches jax top_k/argmax)
        float m0 = v; int i0 = lane;
#pragma unroll
        for (int off = 32; off > 0; off >>= 1) {
            float vo = __shfl_xor(m0, off);
            int   io = __shfl_xor(i0, off);
            if (vo > m0 || (vo == m0 && io < i0)) { m0 = vo; i0 = io; }
        }
        // top-2: exclude i0, same reduce
        float v1 = (lane == i0) ? -3.4e38f : v;
        float m1 = v1; int i1 = lane;
#pragma unroll
        for (int off = 32; off > 0; off >>= 1) {
            float vo = __shfl_xor(m1, off);
            int   io = __shfl_xor(i1, off);
            if (vo > m1 || (vo == m1 && io < i1)) { m1 = vo; i1 = io; }
        }
        // full softmax denom for probs
        const float e = expf(v - m0);
        float s = e;
#pragma unroll
        for (int off = 32; off > 0; off >>= 1) s += __shfl_xor(s, off);
        probLocal += e / s;
        freqLocal += (lane == i0) ? 1.f : 0.f;

        if (lane == 0) {
            const size_t row = (size_t)rowBase + wv * 8 + i;
            const float e1 = expf(m1 - m0);
            const float w0 = 1.f / (1.f + e1);
            out[row * 2 + 0] = w0;
            out[row * 2 + 1] = e1 * w0;
            out[2 * B_ROWS + row * 2 + 0] = (float)i0;   // top_idx as float
            out[2 * B_ROWS + row * 2 + 1] = (float)i1;
        }
    }
    atomicAdd(&sFreq[lane], freqLocal);
    atomicAdd(&sProb[lane], probLocal);
    __syncthreads();
    if (tid < NEXP) {
        atomicAdd(&gFreq[tid], sFreq[tid]);
        atomicAdd(&gProb[tid], sProb[tid]);
    }
}

// ---------------------------------------------------------------------------
__global__ void zero_acc_kernel(float* gAcc) {
    gAcc[threadIdx.x] = 0.f;   // 128 floats: gFreq(64) + gProb(64)
}

__global__ void aux_kernel(const float* __restrict__ gFreq,
                           const float* __restrict__ gProb,
                           float* __restrict__ out) {
    const int lane = threadIdx.x;
    float v = gFreq[lane] * gProb[lane];
#pragma unroll
    for (int off = 32; off > 0; off >>= 1) v += __shfl_xor(v, off);
    if (lane == 0)
        out[4 * B_ROWS] = v * ((float)NEXP / ((float)B_ROWS * (float)B_ROWS));
}

// ---------------------------------------------------------------------------
extern "C" void kernel_launch(void* const* d_in, const int* in_sizes, int n_in,
                              void* d_out, int out_size, void* d_ws, size_t ws_size,
                              hipStream_t stream) {
    const float* x  = (const float*)d_in[0];
    const float* W1 = (const float*)d_in[1];
    const float* b1 = (const float*)d_in[2];
    const float* W2 = (const float*)d_in[3];
    const float* b2 = (const float*)d_in[4];
    float* out = (float*)d_out;

    float* gFreq = (float*)d_ws;                       // 64 floats
    float* gProb = gFreq + 64;                         // 64 floats
    float* h     = (float*)((char*)d_ws + 1024);       // 16384*2048 fp32 = 134 MB

    zero_acc_kernel<<<1, 128, 0, stream>>>(gFreq);

    dim3 g1(HID / BN, B_ROWS / BM);
    gemm1_silu_kernel<<<g1, 256, 0, stream>>>(x, W1, b1, h);

    router_kernel<<<B_ROWS / 32, 256, 0, stream>>>(h, W2, b2, out, gFreq, gProb);

    aux_kernel<<<1, NEXP, 0, stream>>>(gFreq, gProb, out);
}

// Round 2
// 1885.969 us; speedup vs baseline: 2.0054x; 2.0054x over previous
//
#include <hip/hip_runtime.h>
#include <math.h>

#define B_ROWS 16384
#define D_IN   4096
#define HID    2048
#define NEXP   64

typedef __attribute__((ext_vector_type(8))) short short8;
typedef __attribute__((ext_vector_type(4))) float f32x4;

// ---------------------------------------------------------------------------
// bf16 round-to-nearest-even split helpers
// ---------------------------------------------------------------------------
__device__ __forceinline__ unsigned short bf16_rne(float v) {
    unsigned int u = __float_as_uint(v);
    u += 0x7fffu + ((u >> 16) & 1u);
    return (unsigned short)(u >> 16);
}
__device__ __forceinline__ void split2(float v, unsigned short& hi, unsigned short& lo) {
    unsigned short h = bf16_rne(v);
    float hf = __uint_as_float(((unsigned int)h) << 16);
    hi = h;
    lo = bf16_rne(v - hf);
}

// ---------------------------------------------------------------------------
// split x [16384,4096] fp32 -> x_hi, x_lo bf16 (row-major, same layout)
// ---------------------------------------------------------------------------
__global__ __launch_bounds__(256) void split_x_kernel(
    const float* __restrict__ x, unsigned short* __restrict__ hi,
    unsigned short* __restrict__ lo, int n8)
{
    int i = blockIdx.x * 256 + threadIdx.x;
    const int stride = gridDim.x * 256;
    for (; i < n8; i += stride) {
        const float4* src = reinterpret_cast<const float4*>(x + (size_t)i * 8);
        float4 v0 = src[0], v1 = src[1];
        float f[8] = {v0.x, v0.y, v0.z, v0.w, v1.x, v1.y, v1.z, v1.w};
        unsigned short h8[8], l8[8];
#pragma unroll
        for (int j = 0; j < 8; ++j) split2(f[j], h8[j], l8[j]);
        *reinterpret_cast<short8*>(hi + (size_t)i * 8) = *reinterpret_cast<short8*>(h8);
        *reinterpret_cast<short8*>(lo + (size_t)i * 8) = *reinterpret_cast<short8*>(l8);
    }
}

// ---------------------------------------------------------------------------
// split + transpose W1 [4096,2048] fp32 -> W1t_hi/lo [2048,4096] bf16
// ---------------------------------------------------------------------------
__global__ __launch_bounds__(256) void split_w1t_kernel(
    const float* __restrict__ W1, unsigned short* __restrict__ thi,
    unsigned short* __restrict__ tlo)
{
    __shared__ float tile[64][65];
    const int k0 = blockIdx.x * 64;
    const int n0 = blockIdx.y * 64;
    const int tid = threadIdx.x;
#pragma unroll
    for (int it = 0; it < 4; ++it) {
        const int r = it * 16 + (tid >> 4);
        const int c4 = (tid & 15) * 4;
        float4 v = *reinterpret_cast<const float4*>(&W1[(size_t)(k0 + r) * HID + n0 + c4]);
        tile[r][c4 + 0] = v.x; tile[r][c4 + 1] = v.y;
        tile[r][c4 + 2] = v.z; tile[r][c4 + 3] = v.w;
    }
    __syncthreads();
#pragma unroll
    for (int it = 0; it < 2; ++it) {
        const int idx = it * 256 + tid;
        const int n  = idx >> 3;        // 0..63
        const int kc = (idx & 7) * 8;   // k chunk base
        unsigned short h8[8], l8[8];
#pragma unroll
        for (int j = 0; j < 8; ++j) split2(tile[kc + j][n], h8[j], l8[j]);
        const size_t o = (size_t)(n0 + n) * D_IN + k0 + kc;
        *reinterpret_cast<short8*>(thi + o) = *reinterpret_cast<short8*>(h8);
        *reinterpret_cast<short8*>(tlo + o) = *reinterpret_cast<short8*>(l8);
    }
}

// ---------------------------------------------------------------------------
// GEMM1 via bf16 MFMA, 3-term compensated:  h = silu(x@W1 + b1)
// 128x128 tile, BK=32, 4 waves (2x2), 4x4 16x16x32 frags per wave.
// LDS layout k-slot-major: unit u = s*128 + row_local (16B units), so a
// fragment ds_read_b128 walks stride-16B -> balanced banks, and
// global_load_lds's linear "base + lane*16" dest matches exactly.
// ---------------------------------------------------------------------------
__device__ __forceinline__ void gld16(void* lds, const void* g) {
    __builtin_amdgcn_global_load_lds(
        (const __attribute__((address_space(1))) unsigned int*)g,
        (__attribute__((address_space(3))) unsigned int*)lds, 16, 0, 0);
}

__global__ __launch_bounds__(256) void gemm1_mfma_kernel(
    const unsigned short* __restrict__ xhi, const unsigned short* __restrict__ xlo,
    const unsigned short* __restrict__ whi, const unsigned short* __restrict__ wlo,
    const float* __restrict__ b1, float* __restrict__ h)
{
    __shared__ unsigned short Ah[4096], Al[4096], Bh[4096], Bl[4096];

    const int tid  = threadIdx.x;
    const int wave = tid >> 6, lane = tid & 63;
    const int wr = wave >> 1, wc = wave & 1;

    // 16 consecutive blocks share one row tile (A reuse in L2/L3)
    const int bid = blockIdx.x;
    const int bx = bid & 15;          // col tile 0..15
    const int by = bid >> 4;          // row tile 0..127
    const int rowBase = by * 128, colBase = bx * 128;

    f32x4 acc[4][4] = {};

    const int s = lane >> 4, r16 = lane & 15;
    const int aoff = (s * 128 + wr * 64 + r16) * 8;   // ushort elems
    const int boff = (s * 128 + wc * 64 + r16) * 8;

    for (int k0 = 0; k0 < D_IN; k0 += 32) {
        __syncthreads();
#pragma unroll
        for (int t = 0; t < 2; ++t) {
            const int dstu = (wave * 128 + t * 64) * 8;   // wave-uniform elem offset
            const size_t arow = (size_t)(rowBase + t * 64 + lane) * D_IN + k0 + wave * 8;
            const size_t brow = (size_t)(colBase + t * 64 + lane) * D_IN + k0 + wave * 8;
            gld16(&Ah[dstu], &xhi[arow]);
            gld16(&Al[dstu], &xlo[arow]);
            gld16(&Bh[dstu], &whi[brow]);
            gld16(&Bl[dstu], &wlo[brow]);
        }
        __syncthreads();

        short8 avh[4], avl[4], bvh[4], bvl[4];
#pragma unroll
        for (int mf = 0; mf < 4; ++mf) {
            avh[mf] = *reinterpret_cast<const short8*>(&Ah[aoff + mf * 128]);
            avl[mf] = *reinterpret_cast<const short8*>(&Al[aoff + mf * 128]);
        }
#pragma unroll
        for (int nf = 0; nf < 4; ++nf) {
            bvh[nf] = *reinterpret_cast<const short8*>(&Bh[boff + nf * 128]);
            bvl[nf] = *reinterpret_cast<const short8*>(&Bl[boff + nf * 128]);
        }
#pragma unroll
        for (int mf = 0; mf < 4; ++mf)
#pragma unroll
            for (int nf = 0; nf < 4; ++nf) {
                acc[mf][nf] = __builtin_amdgcn_mfma_f32_16x16x32_bf16(
                    avh[mf], bvh[nf], acc[mf][nf], 0, 0, 0);
                acc[mf][nf] = __builtin_amdgcn_mfma_f32_16x16x32_bf16(
                    avh[mf], bvl[nf], acc[mf][nf], 0, 0, 0);
                acc[mf][nf] = __builtin_amdgcn_mfma_f32_16x16x32_bf16(
                    avl[mf], bvh[nf], acc[mf][nf], 0, 0, 0);
            }
    }

    const int r4 = lane >> 4;
#pragma unroll
    for (int mf = 0; mf < 4; ++mf)
#pragma unroll
        for (int nf = 0; nf < 4; ++nf) {
            const int col = colBase + wc * 64 + nf * 16 + r16;
            const float bias = b1[col];
#pragma unroll
            for (int j = 0; j < 4; ++j) {
                const int row = rowBase + wr * 64 + mf * 16 + r4 * 4 + j;
                const float c = acc[mf][nf][j] + bias;
                h[(size_t)row * HID + col] = c / (1.f + __expf(-c));
            }
        }
}

// ---------------------------------------------------------------------------
// Fallback fp32 GEMM1 (round-1 verified) in case ws is too small
// ---------------------------------------------------------------------------
#define BM 128
#define BN 128
#define BK 16
__global__ __launch_bounds__(256) void gemm1_silu_kernel(
    const float* __restrict__ x, const float* __restrict__ W1,
    const float* __restrict__ b1, float* __restrict__ h)
{
    __shared__ float As[BK][BM + 4];
    __shared__ float Bs[BK][BN];
    const int tid = threadIdx.x;
    const int bx = blockIdx.x, by = blockIdx.y;
    const int rowBase = by * BM, colBase = bx * BN;
    const int tx = tid & 15, ty = tid >> 4;
    float acc[8][8];
#pragma unroll
    for (int i = 0; i < 8; ++i)
#pragma unroll
        for (int j = 0; j < 8; ++j) acc[i][j] = 0.f;
    const int ar = tid >> 1, ak = (tid & 1) * 8;
    const int bk = tid >> 4, bc = tid & 15;
    for (int k0 = 0; k0 < D_IN; k0 += BK) {
        {
            const float* src = &x[(size_t)(rowBase + ar) * D_IN + k0 + ak];
            float4 v0 = *reinterpret_cast<const float4*>(src);
            float4 v1 = *reinterpret_cast<const float4*>(src + 4);
            As[ak + 0][ar] = v0.x; As[ak + 1][ar] = v0.y;
            As[ak + 2][ar] = v0.z; As[ak + 3][ar] = v0.w;
            As[ak + 4][ar] = v1.x; As[ak + 5][ar] = v1.y;
            As[ak + 6][ar] = v1.z; As[ak + 7][ar] = v1.w;
        }
        {
            const float4* s4 = reinterpret_cast<const float4*>(
                &W1[(size_t)(k0 + bk) * HID + colBase]);
            float4* d4 = reinterpret_cast<float4*>(&Bs[bk][0]);
            d4[bc] = s4[bc]; d4[bc + 16] = s4[bc + 16];
        }
        __syncthreads();
#pragma unroll
        for (int kk = 0; kk < BK; ++kk) {
            float a[8], b[8];
            *reinterpret_cast<float4*>(&a[0]) = *reinterpret_cast<const float4*>(&As[kk][ty * 8]);
            *reinterpret_cast<float4*>(&a[4]) = *reinterpret_cast<const float4*>(&As[kk][ty * 8 + 4]);
            *reinterpret_cast<float4*>(&b[0]) = *reinterpret_cast<const float4*>(&Bs[kk][tx * 8]);
            *reinterpret_cast<float4*>(&b[4]) = *reinterpret_cast<const float4*>(&Bs[kk][tx * 8 + 4]);
#pragma unroll
            for (int i = 0; i < 8; ++i)
#pragma unroll
                for (int j = 0; j < 8; ++j) acc[i][j] = fmaf(a[i], b[j], acc[i][j]);
        }
        __syncthreads();
    }
#pragma unroll
    for (int i = 0; i < 8; ++i) {
        const size_t row = (size_t)rowBase + ty * 8 + i;
        float o[8];
#pragma unroll
        for (int j = 0; j < 8; ++j) {
            float c = acc[i][j] + b1[colBase + tx * 8 + j];
            o[j] = c / (1.f + expf(-c));
        }
        float4* dst = reinterpret_cast<float4*>(&h[row * HID + colBase + tx * 8]);
        dst[0] = *reinterpret_cast<float4*>(&o[0]);
        dst[1] = *reinterpret_cast<float4*>(&o[4]);
    }
}

// ---------------------------------------------------------------------------
// Router: logits = h @ W2 + b2 fused with top-2 / softmax / stats
// ---------------------------------------------------------------------------
__global__ __launch_bounds__(256) void router_kernel(
    const float* __restrict__ h, const float* __restrict__ W2,
    const float* __restrict__ b2, float* __restrict__ out,
    float* __restrict__ gFreq, float* __restrict__ gProb)
{
    __shared__ float W2s[64][NEXP];
    __shared__ float sFreq[NEXP];
    __shared__ float sProb[NEXP];

    const int tid = threadIdx.x;
    const int lane = tid & 63;
    const int wv = tid >> 6;
    const int rowBase = blockIdx.x * 32;

    if (tid < NEXP) { sFreq[tid] = 0.f; sProb[tid] = 0.f; }

    float acc[8];
#pragma unroll
    for (int i = 0; i < 8; ++i) acc[i] = 0.f;

    const int wk = tid >> 2;
    const int wf = tid & 3;

    for (int k0 = 0; k0 < HID; k0 += 64) {
        __syncthreads();
        {
            const float4* src = reinterpret_cast<const float4*>(&W2[(size_t)(k0 + wk) * NEXP]);
            float4* dst = reinterpret_cast<float4*>(&W2s[wk][0]);
#pragma unroll
            for (int p = 0; p < 4; ++p) dst[wf + 4 * p] = src[wf + 4 * p];
        }
        __syncthreads();

#pragma unroll 2
        for (int kk4 = 0; kk4 < 16; ++kk4) {
            float4 hv[8];
#pragma unroll
            for (int i = 0; i < 8; ++i) {
                const size_t row = (size_t)rowBase + wv * 8 + i;
                hv[i] = *reinterpret_cast<const float4*>(&h[row * HID + k0 + kk4 * 4]);
            }
            {
                const float w = W2s[kk4 * 4 + 0][lane];
#pragma unroll
                for (int i = 0; i < 8; ++i) acc[i] = fmaf(hv[i].x, w, acc[i]);
            }
            {
                const float w = W2s[kk4 * 4 + 1][lane];
#pragma unroll
                for (int i = 0; i < 8; ++i) acc[i] = fmaf(hv[i].y, w, acc[i]);
            }
            {
                const float w = W2s[kk4 * 4 + 2][lane];
#pragma unroll
                for (int i = 0; i < 8; ++i) acc[i] = fmaf(hv[i].z, w, acc[i]);
            }
            {
                const float w = W2s[kk4 * 4 + 3][lane];
#pragma unroll
                for (int i = 0; i < 8; ++i) acc[i] = fmaf(hv[i].w, w, acc[i]);
            }
        }
    }

    float freqLocal = 0.f, probLocal = 0.f;
#pragma unroll
    for (int i = 0; i < 8; ++i) {
        const float v = acc[i] + b2[lane];
        float m0 = v; int i0 = lane;
#pragma unroll
        for (int off = 32; off > 0; off >>= 1) {
            float vo = __shfl_xor(m0, off);
            int   io = __shfl_xor(i0, off);
            if (vo > m0 || (vo == m0 && io < i0)) { m0 = vo; i0 = io; }
        }
        float v1 = (lane == i0) ? -3.4e38f : v;
        float m1 = v1; int i1 = lane;
#pragma unroll
        for (int off = 32; off > 0; off >>= 1) {
            float vo = __shfl_xor(m1, off);
            int   io = __shfl_xor(i1, off);
            if (vo > m1 || (vo == m1 && io < i1)) { m1 = vo; i1 = io; }
        }
        const float e = expf(v - m0);
        float sden = e;
#pragma unroll
        for (int off = 32; off > 0; off >>= 1) sden += __shfl_xor(sden, off);
        probLocal += e / sden;
        freqLocal += (lane == i0) ? 1.f : 0.f;

        if (lane == 0) {
            const size_t row = (size_t)rowBase + wv * 8 + i;
            const float e1 = expf(m1 - m0);
            const float w0 = 1.f / (1.f + e1);
            out[row * 2 + 0] = w0;
            out[row * 2 + 1] = e1 * w0;
            out[2 * B_ROWS + row * 2 + 0] = (float)i0;
            out[2 * B_ROWS + row * 2 + 1] = (float)i1;
        }
    }
    atomicAdd(&sFreq[lane], freqLocal);
    atomicAdd(&sProb[lane], probLocal);
    __syncthreads();
    if (tid < NEXP) {
        atomicAdd(&gFreq[tid], sFreq[tid]);
        atomicAdd(&gProb[tid], sProb[tid]);
    }
}

__global__ void zero_acc_kernel(float* gAcc) { gAcc[threadIdx.x] = 0.f; }

__global__ void aux_kernel(const float* __restrict__ gFreq,
                           const float* __restrict__ gProb,
                           float* __restrict__ out) {
    const int lane = threadIdx.x;
    float v = gFreq[lane] * gProb[lane];
#pragma unroll
    for (int off = 32; off > 0; off >>= 1) v += __shfl_xor(v, off);
    if (lane == 0)
        out[4 * B_ROWS] = v * ((float)NEXP / ((float)B_ROWS * (float)B_ROWS));
}

// ---------------------------------------------------------------------------
extern "C" void kernel_launch(void* const* d_in, const int* in_sizes, int n_in,
                              void* d_out, int out_size, void* d_ws, size_t ws_size,
                              hipStream_t stream) {
    const float* x  = (const float*)d_in[0];
    const float* W1 = (const float*)d_in[1];
    const float* b1 = (const float*)d_in[2];
    const float* W2 = (const float*)d_in[3];
    const float* b2 = (const float*)d_in[4];
    float* out = (float*)d_out;

    float* gFreq = (float*)d_ws;
    float* gProb = gFreq + 64;
    float* h     = (float*)((char*)d_ws + 1024);                   // 134 MB fp32

    const size_t hBytes  = (size_t)B_ROWS * HID * 4;               // 134217728
    const size_t xBytes  = (size_t)B_ROWS * D_IN * 2;              // 134217728
    const size_t wBytes  = (size_t)HID * D_IN * 2;                 // 16777216
    unsigned short* xhi = (unsigned short*)((char*)h + hBytes);
    unsigned short* xlo = (unsigned short*)((char*)xhi + xBytes);
    unsigned short* whi = (unsigned short*)((char*)xlo + xBytes);
    unsigned short* wlo = (unsigned short*)((char*)whi + wBytes);
    const size_t need = 1024 + hBytes + 2 * xBytes + 2 * wBytes;   // ~436 MB

    zero_acc_kernel<<<1, 128, 0, stream>>>(gFreq);

    if (ws_size >= need) {
        const int n8 = (B_ROWS * D_IN) / 8;
        split_x_kernel<<<4096, 256, 0, stream>>>(x, xhi, xlo, n8);
        dim3 gw(D_IN / 64, HID / 64);
        split_w1t_kernel<<<gw, 256, 0, stream>>>(W1, whi, wlo);
        gemm1_mfma_kernel<<<(B_ROWS / 128) * (HID / 128), 256, 0, stream>>>(
            xhi, xlo, whi, wlo, b1, h);
    } else {
        dim3 g1(HID / BN, B_ROWS / BM);
        gemm1_silu_kernel<<<g1, 256, 0, stream>>>(x, W1, b1, h);
    }

    router_kernel<<<B_ROWS / 32, 256, 0, stream>>>(h, W2, b2, out, gFreq, gProb);
    aux_kernel<<<1, NEXP, 0, stream>>>(gFreq, gProb, out);
}

// Round 3
// 1876.445 us; speedup vs baseline: 2.0156x; 1.0051x over previous
//
#include <hip/hip_runtime.h>
#include <math.h>

#define B_ROWS 16384
#define D_IN   4096
#define HID    2048
#define NEXP   64
#define NT     384      // virtual K' = 3*4096, BK=32 -> 384 k-tiles

typedef __attribute__((ext_vector_type(8))) short short8;
typedef __attribute__((ext_vector_type(4))) float f32x4;

#define VMCNT(n) asm volatile("s_waitcnt vmcnt(%0)" :: "i"(n) : "memory")
#define GATE() do { __builtin_amdgcn_sched_barrier(0); __builtin_amdgcn_s_barrier(); \
                    __builtin_amdgcn_sched_barrier(0); } while (0)

// ---------------------------------------------------------------------------
// bf16 split helpers
// ---------------------------------------------------------------------------
__device__ __forceinline__ unsigned short bf16_rne(float v) {
    unsigned int u = __float_as_uint(v);
    u += 0x7fffu + ((u >> 16) & 1u);
    return (unsigned short)(u >> 16);
}
__device__ __forceinline__ void split2(float v, unsigned short& hi, unsigned short& lo) {
    unsigned short h = bf16_rne(v);
    float hf = __uint_as_float(((unsigned int)h) << 16);
    hi = h;
    lo = bf16_rne(v - hf);
}

// ---------------------------------------------------------------------------
__global__ __launch_bounds__(256) void split_x_kernel(
    const float* __restrict__ x, unsigned short* __restrict__ hi,
    unsigned short* __restrict__ lo, int n8)
{
    int i = blockIdx.x * 256 + threadIdx.x;
    const int stride = gridDim.x * 256;
    for (; i < n8; i += stride) {
        const float4* src = reinterpret_cast<const float4*>(x + (size_t)i * 8);
        float4 v0 = src[0], v1 = src[1];
        float f[8] = {v0.x, v0.y, v0.z, v0.w, v1.x, v1.y, v1.z, v1.w};
        unsigned short h8[8], l8[8];
#pragma unroll
        for (int j = 0; j < 8; ++j) split2(f[j], h8[j], l8[j]);
        *reinterpret_cast<short8*>(hi + (size_t)i * 8) = *reinterpret_cast<short8*>(h8);
        *reinterpret_cast<short8*>(lo + (size_t)i * 8) = *reinterpret_cast<short8*>(l8);
    }
}

// split + transpose W1 [4096,2048] -> W1t hi/lo [2048,4096]
__global__ __launch_bounds__(256) void split_w1t_kernel(
    const float* __restrict__ W1, unsigned short* __restrict__ thi,
    unsigned short* __restrict__ tlo)
{
    __shared__ float tile[64][65];
    const int k0 = blockIdx.x * 64;
    const int n0 = blockIdx.y * 64;
    const int tid = threadIdx.x;
#pragma unroll
    for (int it = 0; it < 4; ++it) {
        const int r = it * 16 + (tid >> 4);
        const int c4 = (tid & 15) * 4;
        float4 v = *reinterpret_cast<const float4*>(&W1[(size_t)(k0 + r) * HID + n0 + c4]);
        tile[r][c4 + 0] = v.x; tile[r][c4 + 1] = v.y;
        tile[r][c4 + 2] = v.z; tile[r][c4 + 3] = v.w;
    }
    __syncthreads();
#pragma unroll
    for (int it = 0; it < 2; ++it) {
        const int idx = it * 256 + tid;
        const int n  = idx >> 3;
        const int kc = (idx & 7) * 8;
        unsigned short h8[8], l8[8];
#pragma unroll
        for (int j = 0; j < 8; ++j) split2(tile[kc + j][n], h8[j], l8[j]);
        const size_t o = (size_t)(n0 + n) * D_IN + k0 + kc;
        *reinterpret_cast<short8*>(thi + o) = *reinterpret_cast<short8*>(h8);
        *reinterpret_cast<short8*>(tlo + o) = *reinterpret_cast<short8*>(l8);
    }
}

// ---------------------------------------------------------------------------
__device__ __forceinline__ void gld16(void* lds_p, const void* g) {
    __builtin_amdgcn_global_load_lds(
        (const __attribute__((address_space(1))) unsigned int*)g,
        (__attribute__((address_space(3))) unsigned int*)lds_p, 16, 0, 0);
}

// ---------------------------------------------------------------------------
// GEMM1, 8-phase pipelined, virtual-K 3-term compensated bf16.
// 256x256 tile, BK=32, 8 waves (2Mx4N), 4 LDS buffers, prefetch 3 tiles ahead,
// counted vmcnt(8) per tile. LDS k-slot-major: unit = s*256 + row (16B units),
// conflict-free (verified 0 conflicts in R2) and global_load_lds linear-dest OK.
// ---------------------------------------------------------------------------
__global__ __launch_bounds__(512) void gemm1_8ph_kernel(
    const unsigned short* __restrict__ xhi, const unsigned short* __restrict__ xlo,
    const unsigned short* __restrict__ whi, const unsigned short* __restrict__ wlo,
    const float* __restrict__ b1, float* __restrict__ h)
{
    __shared__ __align__(16) unsigned short lds[4][2][1024][8];  // 128 KiB

    const int tid  = threadIdx.x;
    const int lane = tid & 63, wid = tid >> 6;
    const int wr = wid >> 2, wc = wid & 3;

    // XCD-aware swizzle: 512 wgs, 8 XCDs, 64 per XCD (bijective, 512%8==0)
    const int bid = blockIdx.x;
    const int wg  = (bid & 7) * 64 + (bid >> 3);
    const int rid = wg >> 3, cid = wg & 7;
    const int rowBase = rid * 256, colBase = cid * 256;

    // staging decomposition: thread t stages units {t, 512+t} of each A/B region
    const int sv    = tid >> 8;     // s bit for first unit
    const int rrow  = tid & 255;    // row (A) / col (B) within tile
    const int ubase = tid & 448;    // wid*64 : wave-uniform dest unit base

    // fragment read element-offsets (within a [1024][8] region)
    const int afo = ((((lane >> 4) << 8) + (wr << 7) + (lane & 15)) << 3);
    const int bfo = ((((lane >> 4) << 8) + (wc << 6) + (lane & 15)) << 3);

    f32x4 acc[8][4];
#pragma unroll
    for (int i = 0; i < 8; ++i)
#pragma unroll
        for (int j = 0; j < 4; ++j) { acc[i][j][0]=0.f; acc[i][j][1]=0.f; acc[i][j][2]=0.f; acc[i][j][3]=0.f; }

    auto stage_pair = [&](int t, int ab) {
        const int term = t >> 7;
        const int kin  = (t & 127) << 5;
        const unsigned short* src;
        size_t base;
        if (ab == 0) {
            src  = (term < 2) ? xhi : xlo;
            base = (size_t)(rowBase + rrow) * D_IN + kin;
        } else {
            src  = (term == 1) ? wlo : whi;
            base = (size_t)(colBase + rrow) * D_IN + kin;
        }
        const int buf = t & 3;
        gld16(&lds[buf][ab][ubase][0],       src + base + sv * 8);
        gld16(&lds[buf][ab][512 + ubase][0], src + base + (2 + sv) * 8);
    };

    // prologue: tiles 0,1,2 fully staged (12 loads); wait tile0 (8 outstanding)
    stage_pair(0, 0); stage_pair(0, 1);
    stage_pair(1, 0); stage_pair(1, 1);
    stage_pair(2, 0); stage_pair(2, 1);
    VMCNT(8);
    GATE();

    short8 afr[8], bfr[4];

    for (int t = 0; t < NT; ++t) {
        const unsigned short* bufA = &lds[t & 3][0][0][0];
        const unsigned short* bufB = &lds[t & 3][1][0][0];

        // ---- phase 0: B frags + A mf0-3, stage A of tile t+3 ----
#pragma unroll
        for (int nf = 0; nf < 4; ++nf)
            bfr[nf] = *reinterpret_cast<const short8*>(bufB + bfo + nf * 128);
#pragma unroll
        for (int mf = 0; mf < 4; ++mf)
            afr[mf] = *reinterpret_cast<const short8*>(bufA + afo + mf * 128);
        if (t + 3 < NT) stage_pair(t + 3, 0);
        GATE();
        __builtin_amdgcn_s_setprio(1);
#pragma unroll
        for (int mf = 0; mf < 4; ++mf)
#pragma unroll
            for (int nf = 0; nf < 4; ++nf)
                acc[mf][nf] = __builtin_amdgcn_mfma_f32_16x16x32_bf16(
                    afr[mf], bfr[nf], acc[mf][nf], 0, 0, 0);
        __builtin_amdgcn_s_setprio(0);
        GATE();

        // ---- phase 1: A mf4-7, stage B of tile t+3 ----
#pragma unroll
        for (int mf = 4; mf < 8; ++mf)
            afr[mf] = *reinterpret_cast<const short8*>(bufA + afo + mf * 128);
        if (t + 3 < NT) stage_pair(t + 3, 1);
        GATE();
        __builtin_amdgcn_s_setprio(1);
#pragma unroll
        for (int mf = 4; mf < 8; ++mf)
#pragma unroll
            for (int nf = 0; nf < 4; ++nf)
                acc[mf][nf] = __builtin_amdgcn_mfma_f32_16x16x32_bf16(
                    afr[mf], bfr[nf], acc[mf][nf], 0, 0, 0);
        __builtin_amdgcn_s_setprio(0);
        // tile-end wait: next tile's data must be landed after the barrier
        if (t < NT - 3)       { VMCNT(8); }
        else if (t == NT - 3) { VMCNT(4); }
        else if (t == NT - 2) { VMCNT(0); }
        GATE();
    }

    // ---- epilogue: bias + SiLU + store h (fp32) ----
    const int r16 = lane & 15, r4 = lane >> 4;
#pragma unroll
    for (int nf = 0; nf < 4; ++nf) {
        const int col = colBase + wc * 64 + nf * 16 + r16;
        const float bias = b1[col];
#pragma unroll
        for (int mf = 0; mf < 8; ++mf) {
#pragma unroll
            for (int j = 0; j < 4; ++j) {
                const int row = rowBase + wr * 128 + mf * 16 + r4 * 4 + j;
                const float c = acc[mf][nf][j] + bias;
                h[(size_t)row * HID + col] = c / (1.f + __expf(-c));
            }
        }
    }
}

// ---------------------------------------------------------------------------
// Fallback fp32 GEMM1 (verified R1) if workspace too small
// ---------------------------------------------------------------------------
#define BM 128
#define BN 128
#define BK 16
__global__ __launch_bounds__(256) void gemm1_silu_kernel(
    const float* __restrict__ x, const float* __restrict__ W1,
    const float* __restrict__ b1, float* __restrict__ h)
{
    __shared__ float As[BK][BM + 4];
    __shared__ float Bs[BK][BN];
    const int tid = threadIdx.x;
    const int bx = blockIdx.x, by = blockIdx.y;
    const int rowBase = by * BM, colBase = bx * BN;
    const int tx = tid & 15, ty = tid >> 4;
    float acc[8][8];
#pragma unroll
    for (int i = 0; i < 8; ++i)
#pragma unroll
        for (int j = 0; j < 8; ++j) acc[i][j] = 0.f;
    const int ar = tid >> 1, ak = (tid & 1) * 8;
    const int bk = tid >> 4, bc = tid & 15;
    for (int k0 = 0; k0 < D_IN; k0 += BK) {
        {
            const float* src = &x[(size_t)(rowBase + ar) * D_IN + k0 + ak];
            float4 v0 = *reinterpret_cast<const float4*>(src);
            float4 v1 = *reinterpret_cast<const float4*>(src + 4);
            As[ak + 0][ar] = v0.x; As[ak + 1][ar] = v0.y;
            As[ak + 2][ar] = v0.z; As[ak + 3][ar] = v0.w;
            As[ak + 4][ar] = v1.x; As[ak + 5][ar] = v1.y;
            As[ak + 6][ar] = v1.z; As[ak + 7][ar] = v1.w;
        }
        {
            const float4* s4 = reinterpret_cast<const float4*>(
                &W1[(size_t)(k0 + bk) * HID + colBase]);
            float4* d4 = reinterpret_cast<float4*>(&Bs[bk][0]);
            d4[bc] = s4[bc]; d4[bc + 16] = s4[bc + 16];
        }
        __syncthreads();
#pragma unroll
        for (int kk = 0; kk < BK; ++kk) {
            float a[8], b[8];
            *reinterpret_cast<float4*>(&a[0]) = *reinterpret_cast<const float4*>(&As[kk][ty * 8]);
            *reinterpret_cast<float4*>(&a[4]) = *reinterpret_cast<const float4*>(&As[kk][ty * 8 + 4]);
            *reinterpret_cast<float4*>(&b[0]) = *reinterpret_cast<const float4*>(&Bs[kk][tx * 8]);
            *reinterpret_cast<float4*>(&b[4]) = *reinterpret_cast<const float4*>(&Bs[kk][tx * 8 + 4]);
#pragma unroll
            for (int i = 0; i < 8; ++i)
#pragma unroll
                for (int j = 0; j < 8; ++j) acc[i][j] = fmaf(a[i], b[j], acc[i][j]);
        }
        __syncthreads();
    }
#pragma unroll
    for (int i = 0; i < 8; ++i) {
        const size_t row = (size_t)rowBase + ty * 8 + i;
        float o[8];
#pragma unroll
        for (int j = 0; j < 8; ++j) {
            float c = acc[i][j] + b1[colBase + tx * 8 + j];
            o[j] = c / (1.f + expf(-c));
        }
        float4* dst = reinterpret_cast<float4*>(&h[row * HID + colBase + tx * 8]);
        dst[0] = *reinterpret_cast<float4*>(&o[0]);
        dst[1] = *reinterpret_cast<float4*>(&o[4]);
    }
}

// ---------------------------------------------------------------------------
// Router v2: no LDS staging / no per-chunk syncs; W2 read direct (L2-resident),
// k unrolled by 8 so loads pipeline. Top-2/softmax/stats epilogue verbatim R1.
// ---------------------------------------------------------------------------
__global__ __launch_bounds__(256) void router2_kernel(
    const float* __restrict__ h, const float* __restrict__ W2,
    const float* __restrict__ b2, float* __restrict__ out,
    float* __restrict__ gFreq, float* __restrict__ gProb)
{
    __shared__ float sFreq[NEXP], sProb[NEXP];
    const int tid = threadIdx.x, lane = tid & 63, wv = tid >> 6;
    const size_t rowBase = (size_t)blockIdx.x * 32 + (size_t)wv * 8;
    if (tid < NEXP) { sFreq[tid] = 0.f; sProb[tid] = 0.f; }

    float acc[8] = {0.f, 0.f, 0.f, 0.f, 0.f, 0.f, 0.f, 0.f};

#pragma unroll 2
    for (int k0 = 0; k0 < HID; k0 += 8) {
        float w2r[8];
#pragma unroll
        for (int j = 0; j < 8; ++j) w2r[j] = W2[(size_t)(k0 + j) * NEXP + lane];
#pragma unroll
        for (int i = 0; i < 8; ++i) {
            const float4 h0 = *reinterpret_cast<const float4*>(&h[(rowBase + i) * HID + k0]);
            const float4 h1 = *reinterpret_cast<const float4*>(&h[(rowBase + i) * HID + k0 + 4]);
            acc[i] += h0.x * w2r[0] + h0.y * w2r[1] + h0.z * w2r[2] + h0.w * w2r[3]
                    + h1.x * w2r[4] + h1.y * w2r[5] + h1.z * w2r[6] + h1.w * w2r[7];
        }
    }

    __syncthreads();   // sFreq/sProb init visible before atomics

    float freqLocal = 0.f, probLocal = 0.f;
#pragma unroll
    for (int i = 0; i < 8; ++i) {
        const float v = acc[i] + b2[lane];
        float m0 = v; int i0 = lane;
#pragma unroll
        for (int off = 32; off > 0; off >>= 1) {
            float vo = __shfl_xor(m0, off);
            int   io = __shfl_xor(i0, off);
            if (vo > m0 || (vo == m0 && io < i0)) { m0 = vo; i0 = io; }
        }
        float v1 = (lane == i0) ? -3.4e38f : v;
        float m1 = v1; int i1 = lane;
#pragma unroll
        for (int off = 32; off > 0; off >>= 1) {
            float vo = __shfl_xor(m1, off);
            int   io = __shfl_xor(i1, off);
            if (vo > m1 || (vo == m1 && io < i1)) { m1 = vo; i1 = io; }
        }
        const float e = expf(v - m0);
        float sden = e;
#pragma unroll
        for (int off = 32; off > 0; off >>= 1) sden += __shfl_xor(sden, off);
        probLocal += e / sden;
        freqLocal += (lane == i0) ? 1.f : 0.f;

        if (lane == 0) {
            const size_t row = rowBase + i;
            const float e1 = expf(m1 - m0);
            const float w0 = 1.f / (1.f + e1);
            out[row * 2 + 0] = w0;
            out[row * 2 + 1] = e1 * w0;
            out[2 * B_ROWS + row * 2 + 0] = (float)i0;
            out[2 * B_ROWS + row * 2 + 1] = (float)i1;
        }
    }
    atomicAdd(&sFreq[lane], freqLocal);
    atomicAdd(&sProb[lane], probLocal);
    __syncthreads();
    if (tid < NEXP) {
        atomicAdd(&gFreq[tid], sFreq[tid]);
        atomicAdd(&gProb[tid], sProb[tid]);
    }
}

__global__ void zero_acc_kernel(float* gAcc) { gAcc[threadIdx.x] = 0.f; }

__global__ void aux_kernel(const float* __restrict__ gFreq,
                           const float* __restrict__ gProb,
                           float* __restrict__ out) {
    const int lane = threadIdx.x;
    float v = gFreq[lane] * gProb[lane];
#pragma unroll
    for (int off = 32; off > 0; off >>= 1) v += __shfl_xor(v, off);
    if (lane == 0)
        out[4 * B_ROWS] = v * ((float)NEXP / ((float)B_ROWS * (float)B_ROWS));
}

// ---------------------------------------------------------------------------
extern "C" void kernel_launch(void* const* d_in, const int* in_sizes, int n_in,
                              void* d_out, int out_size, void* d_ws, size_t ws_size,
                              hipStream_t stream) {
    const float* x  = (const float*)d_in[0];
    const float* W1 = (const float*)d_in[1];
    const float* b1 = (const float*)d_in[2];
    const float* W2 = (const float*)d_in[3];
    const float* b2 = (const float*)d_in[4];
    float* out = (float*)d_out;

    float* gFreq = (float*)d_ws;
    float* gProb = gFreq + 64;
    float* h     = (float*)((char*)d_ws + 1024);

    const size_t hBytes = (size_t)B_ROWS * HID * 4;
    const size_t xBytes = (size_t)B_ROWS * D_IN * 2;
    const size_t wBytes = (size_t)HID * D_IN * 2;
    unsigned short* xhi = (unsigned short*)((char*)h + hBytes);
    unsigned short* xlo = (unsigned short*)((char*)xhi + xBytes);
    unsigned short* whi = (unsigned short*)((char*)xlo + xBytes);
    unsigned short* wlo = (unsigned short*)((char*)whi + wBytes);
    const size_t need = 1024 + hBytes + 2 * xBytes + 2 * wBytes;

    zero_acc_kernel<<<1, 128, 0, stream>>>(gFreq);

    if (ws_size >= need) {
        const int n8 = (B_ROWS * D_IN) / 8;
        split_x_kernel<<<4096, 256, 0, stream>>>(x, xhi, xlo, n8);
        dim3 gw(D_IN / 64, HID / 64);
        split_w1t_kernel<<<gw, 256, 0, stream>>>(W1, whi, wlo);
        gemm1_8ph_kernel<<<512, 512, 0, stream>>>(xhi, xlo, whi, wlo, b1, h);
    } else {
        dim3 g1(HID / BN, B_ROWS / BM);
        gemm1_silu_kernel<<<g1, 256, 0, stream>>>(x, W1, b1, h);
    }

    router2_kernel<<<B_ROWS / 32, 256, 0, stream>>>(h, W2, b2, out, gFreq, gProb);
    aux_kernel<<<1, NEXP, 0, stream>>>(gFreq, gProb, out);
}